// Round 3
// baseline (1299.034 us; speedup 1.0000x reference)
//
#include <hip/hip_runtime.h>
#include <hip/hip_bf16.h>
#include <stdint.h>

// GCNDecoder, ws_size-adaptive:
//  Tier A (ws >= ~512MB): store Y4,Y1 (bf16) + aliased out1/Y2; 3 GEMM passes + gemv.
//  Tier B (ws >= ~256MB): store only Y1; recompute Y4 via LDS-chained GEMM; partial dots into out.
//  Tier C (ws >= ~0.4MB): full recompute chains, no big buffers; all dots atomically into out.
// All BN stats are fused column sum/sumsq (fp32 atomics) in GEMM epilogues; k_stats converts to
// per-col (a, c_std, c_biasfolded). bf16 storage/compute with fp32 MFMA accumulation.

typedef __attribute__((ext_vector_type(8))) short short8;
typedef __attribute__((ext_vector_type(4))) float f32x4;

__device__ __forceinline__ unsigned short bf16b(float f) {
  unsigned int u = __float_as_uint(f);
  return (unsigned short)((u + 0x7fffu + ((u >> 16) & 1u)) >> 16);  // RNE
}
__device__ __forceinline__ unsigned int packbf(float lo, float hi) {
  return (unsigned int)bf16b(lo) | ((unsigned int)bf16b(hi) << 16);
}
__device__ __forceinline__ float bflo(unsigned int u) { return __uint_as_float(u << 16); }
__device__ __forceinline__ float bfhi(unsigned int u) { return __uint_as_float(u & 0xffff0000u); }
__device__ __forceinline__ float bfs(short s) { return __uint_as_float(((unsigned int)(unsigned short)s) << 16); }
__device__ __forceinline__ float relu_(float x) { return fmaxf(x, 0.0f); }

// ---------------- tiny kernels ----------------
__global__ __launch_bounds__(256) void k_init(const int* __restrict__ ei,
                                              float* __restrict__ stats, int* __restrict__ flag) {
  const int t = threadIdx.x;
#pragma unroll
  for (int i = 0; i < 6; ++i) stats[t + 256 * i] = 0.f;
  if (t == 0) {
    int o = 0;
#pragma unroll
    for (int i = 0; i < 32; ++i) o |= ei[2 * i + 1];
    *flag = (o == 0) ? 1 : 0;  // 1 => int64 pairs, 0 => int32
  }
}

__global__ __launch_bounds__(256) void k_zero(float* __restrict__ out, const float* __restrict__ bfp, int E) {
  const int i = blockIdx.x * 256 + threadIdx.x;
  if (i < E) out[i] = bfp[0];
}

__global__ __launch_bounds__(256) void k_prep(
    const float* __restrict__ W4, const float* __restrict__ W1, const float* __restrict__ W2,
    unsigned short* __restrict__ wt4, unsigned short* __restrict__ wt1, unsigned short* __restrict__ wt2)
{
  const int b = blockIdx.x;           // 0..191
  const int t = threadIdx.x;
  const int wi = b >> 6;
  const int r = b & 63;
  const float* W = (wi == 0) ? W4 : (wi == 1) ? W1 : W2;
  unsigned short* Wt = (wi == 0) ? wt4 : (wi == 1) ? wt1 : wt2;
  const int flat = r * 1024 + t * 4;  // Wt[n][k] = W[k][n]
  const int n = flat >> 8;
  const int k = flat & 255;
  ushort4 o;
  o.x = bf16b(W[(k + 0) * 256 + n]);
  o.y = bf16b(W[(k + 1) * 256 + n]);
  o.z = bf16b(W[(k + 2) * 256 + n]);
  o.w = bf16b(W[(k + 3) * 256 + n]);
  *(ushort4*)(Wt + flat) = o;
}

// stats -> a = g*rsqrt(var+eps); c_std = be - mean*a; c_b = a*bias + c_std
__global__ __launch_bounds__(256) void k_stats(
    const float* __restrict__ stats, const float* __restrict__ g, const float* __restrict__ be,
    const float* __restrict__ bias, float* __restrict__ scale, float invE)
{
  const int c = threadIdx.x;
  const float mean = stats[c] * invE;
  const float var = stats[256 + c] * invE - mean * mean;
  const float a = g[c] * rsqrtf(var + 1e-5f);
  const float cstd = be[c] - mean * a;
  scale[c] = a;
  scale[256 + c] = cstd;
  scale[512 + c] = fmaf(a, bias[c], cstd);
}

// ---------------- shared epilogue: bias add, optional bf16 store, optional stats ----------------
template<bool STORE, bool STATS>
__device__ __forceinline__ void dev_epilogue(f32x4 acc[4][4], const float* __restrict__ bias,
    unsigned short* __restrict__ Yout, float* __restrict__ stats, int m0, int E, int t)
{
  const int l = t & 63;
  const int wv = t >> 6;
  const int wr = wv >> 2;
  const int wc = wv & 3;
  const int colb = wc * 64 + (l & 15);
  float bj[4];
#pragma unroll
  for (int j = 0; j < 4; ++j) bj[j] = bias[colb + j * 16];

  float ssum[4] = {0.f, 0.f, 0.f, 0.f};
  float ssq[4] = {0.f, 0.f, 0.f, 0.f};
  const int rbase = m0 + wr * 64 + ((l >> 4) << 2);
  const int odd = l & 1;

#pragma unroll
  for (int i = 0; i < 4; ++i) {
#pragma unroll
    for (int j = 0; j < 4; ++j) {
      float v0 = acc[i][j][0] + bj[j];
      float v1 = acc[i][j][1] + bj[j];
      float v2 = acc[i][j][2] + bj[j];
      float v3 = acc[i][j][3] + bj[j];
      const int r0 = rbase + i * 16;
      if (STATS) {
        if (r0 + 0 < E) { ssum[j] += v0; ssq[j] = fmaf(v0, v0, ssq[j]); }
        if (r0 + 1 < E) { ssum[j] += v1; ssq[j] = fmaf(v1, v1, ssq[j]); }
        if (r0 + 2 < E) { ssum[j] += v2; ssq[j] = fmaf(v2, v2, ssq[j]); }
        if (r0 + 3 < E) { ssum[j] += v3; ssq[j] = fmaf(v3, v3, ssq[j]); }
      }
      if (STORE) {
        float p0 = __shfl_xor(v0, 1);
        float p1 = __shfl_xor(v1, 1);
        float p2 = __shfl_xor(v2, 1);
        float p3 = __shfl_xor(v3, 1);
        float loA = odd ? p2 : v0;
        float hiA = odd ? v2 : p0;
        float loB = odd ? p3 : v1;
        float hiB = odd ? v3 : p1;
        const int ra = r0 + (odd ? 2 : 0);
        const int cp = (colb + j * 16) & ~1;
        *(unsigned int*)(Yout + (size_t)(ra + 0) * 256 + cp) = packbf(loA, hiA);
        *(unsigned int*)(Yout + (size_t)(ra + 1) * 256 + cp) = packbf(loB, hiB);
      }
    }
  }

  if (STATS) {
#pragma unroll
    for (int j = 0; j < 4; ++j) {
      ssum[j] += __shfl_xor(ssum[j], 16); ssum[j] += __shfl_xor(ssum[j], 32);
      ssq[j]  += __shfl_xor(ssq[j], 16);  ssq[j]  += __shfl_xor(ssq[j], 32);
    }
    const int g = l >> 4;
    float sg = (g == 0) ? ssum[0] : (g == 1) ? ssum[1] : (g == 2) ? ssum[2] : ssum[3];
    float qg = (g == 0) ? ssq[0] : (g == 1) ? ssq[1] : (g == 2) ? ssq[2] : ssq[3];
    const int col = wc * 64 + g * 16 + (l & 15);
    atomicAdd(&stats[col], sg);
    atomicAdd(&stats[256 + col], qg);
  }
}

// ---------------- chain-kernel device pieces (hA = 128x256 bf16, 512B rows, XOR-swizzled) ----------------
__device__ __forceinline__ void dev_stage_gather(char* hA, const float* __restrict__ x,
                                                 int sN, int dN, int t)
{
  const int row = t & 127;
  const int cg = t >> 7;              // 0..3 -> 64-col groups (concat boundary at 128)
  const int node = (cg < 2) ? sN : dN;
  const float* src = x + node * 128 + (cg & 1) * 64;
  const int swr = (row & 7) << 4;
  char* hp = hA + row * 512;
#pragma unroll
  for (int u = 0; u < 8; ++u) {
    float4 f0 = *(const float4*)(src + u * 8);
    float4 f1 = *(const float4*)(src + u * 8 + 4);
    uint4 v;
    v.x = packbf(f0.x, f0.y); v.y = packbf(f0.z, f0.w);
    v.z = packbf(f1.x, f1.y); v.w = packbf(f1.z, f1.w);
    *(uint4*)(hp + ((cg * 128 + u * 16) ^ swr)) = v;
  }
}

__device__ __forceinline__ void dev_gemm_hA(f32x4 acc[4][4], const char* hA, char* bT,
                                            const unsigned short* __restrict__ Wt, int t)
{
  const int l = t & 63, wv = t >> 6, wr = wv >> 2, wc = wv & 3;
  const int sw = (l & 7) << 4;
  const int brow = t & 255, bh = t >> 8;
  f32x4 zz = {0.f, 0.f, 0.f, 0.f};
#pragma unroll
  for (int i = 0; i < 4; ++i)
#pragma unroll
    for (int j = 0; j < 4; ++j) acc[i][j] = zz;

  for (int ks = 0; ks < 4; ++ks) {
    const unsigned short* srcb = Wt + brow * 256 + ks * 64 + bh * 32;
    uint4 b0 = *(const uint4*)(srcb);
    uint4 b1 = *(const uint4*)(srcb + 8);
    uint4 b2 = *(const uint4*)(srcb + 16);
    uint4 b3 = *(const uint4*)(srcb + 24);
    __syncthreads();   // prev-ks bT reads done; (ks==0) prior hA writes visible
    char* bp = bT + brow * 128;
    const int swb = (brow & 7) << 4;
    const int kcb = bh * 4;
    *(uint4*)(bp + (((kcb + 0) * 16) ^ swb)) = b0;
    *(uint4*)(bp + (((kcb + 1) * 16) ^ swb)) = b1;
    *(uint4*)(bp + (((kcb + 2) * 16) ^ swb)) = b2;
    *(uint4*)(bp + (((kcb + 3) * 16) ^ swb)) = b3;
    __syncthreads();
    const int ar = wr * 64 + (l & 15);
    const int bn = wc * 64 + (l & 15);
#pragma unroll
    for (int kk = 0; kk < 2; ++kk) {
      const int kbA = ks * 128 + kk * 64 + ((l >> 4) << 4);
      const int kbB = kk * 64 + ((l >> 4) << 4);
      short8 af[4], bfr[4];
#pragma unroll
      for (int i = 0; i < 4; ++i)
        af[i] = *(const short8*)(hA + (ar + i * 16) * 512 + (kbA ^ sw));
#pragma unroll
      for (int j = 0; j < 4; ++j)
        bfr[j] = *(const short8*)(bT + (bn + j * 16) * 128 + (kbB ^ sw));
#pragma unroll
      for (int i = 0; i < 4; ++i)
#pragma unroll
        for (int j = 0; j < 4; ++j)
          acc[i][j] = __builtin_amdgcn_mfma_f32_16x16x32_bf16(af[i], bfr[j], acc[i][j], 0, 0, 0);
    }
  }
  __syncthreads();   // hA/bT free to overwrite after this
}

// acc (raw, no bias) -> relu(a*acc + c_b) [+ resid from hA] -> bf16 into hA
template<bool RESID>
__device__ __forceinline__ void dev_act_to_hA(f32x4 acc[4][4], char* hA, const float* sS,
                                              int base, int t)
{
  const int l = t & 63, wv = t >> 6, wr = wv >> 2, wc = wv & 3;
  const int r0 = wr * 64 + ((l >> 4) << 2);
#pragma unroll
  for (int j = 0; j < 4; ++j) {
    const int col = wc * 64 + (l & 15) + j * 16;
    const float a = sS[base + col], cb = sS[base + 512 + col];
#pragma unroll
    for (int i = 0; i < 4; ++i) {
#pragma unroll
      for (int q = 0; q < 4; ++q) {
        const int row = r0 + i * 16 + q;
        char* p = hA + row * 512 + (((col * 2)) ^ ((row & 7) << 4));
        float v = relu_(fmaf(acc[i][j][q], a, cb));
        if (RESID) v += bfs(*(const short*)p);
        *(unsigned short*)p = bf16b(v);
      }
    }
  }
}

// final dot: out2 = relu(a2*acc + cb2) + out1(hA); out[row] += out2 . wf
__device__ __forceinline__ void dev_dot_emit(f32x4 acc[4][4], const char* hA, const float* sS,
                                             float* __restrict__ out, int m0, int E, int t)
{
  const int l = t & 63, wv = t >> 6, wr = wv >> 2, wc = wv & 3;
  const int r0 = wr * 64 + ((l >> 4) << 2);
  float part[4][4];
#pragma unroll
  for (int i = 0; i < 4; ++i)
#pragma unroll
    for (int q = 0; q < 4; ++q) part[i][q] = 0.f;
#pragma unroll
  for (int j = 0; j < 4; ++j) {
    const int col = wc * 64 + (l & 15) + j * 16;
    const float a2 = sS[1536 + col], cb2 = sS[2048 + col], wfv = sS[2304 + col];
#pragma unroll
    for (int i = 0; i < 4; ++i) {
#pragma unroll
      for (int q = 0; q < 4; ++q) {
        const int row = r0 + i * 16 + q;
        const float o1 = bfs(*(const short*)(hA + row * 512 + (((col * 2)) ^ ((row & 7) << 4))));
        const float v = relu_(fmaf(acc[i][j][q], a2, cb2)) + o1;
        part[i][q] = fmaf(v, wfv, part[i][q]);
      }
    }
  }
#pragma unroll
  for (int i = 0; i < 4; ++i)
#pragma unroll
    for (int q = 0; q < 4; ++q) {
      float p = part[i][q];
      p += __shfl_xor(p, 1); p += __shfl_xor(p, 2); p += __shfl_xor(p, 4); p += __shfl_xor(p, 8);
      if ((l & 15) == 0) {
        const int row = m0 + r0 + i * 16 + q;
        if (row < E) atomicAdd(&out[row], p);
      }
    }
}

__device__ __forceinline__ unsigned int k5pair(unsigned int y, float h0, float h1,
                                               const float* sS, int col, float& dot) {
  float lo = relu_(fmaf(bflo(y), sS[768 + col], sS[1024 + col])) + h0;
  float hi = relu_(fmaf(bfhi(y), sS[768 + col + 1], sS[1024 + col + 1])) + h1;
  dot = fmaf(lo, sS[2304 + col], fmaf(hi, sS[2304 + col + 1], dot));
  return packbf(lo, hi);
}

// ---------------- chain kernel ----------------
// KIND 0: G4 -> stats4
// KIND 1: G4,act4,G1 -> stats1 + store Y1        (Tier B)
// KIND 2: G4,act4,G1 -> stats1                   (Tier C)
// KIND 3: G4,act4,G1,act1+res,G2 -> stats2       (Tier C)
// KIND 4: G4,act4,G1,act1+res,G2 -> dot into out (Tier C)
// KIND 5: G4,act4,[load Y1,act1,+h,dot out1,writeback],G2 -> stats2 + store Y2 (Tier B)
template<int KIND>
__global__ __launch_bounds__(512) void k_chain(
    const float* __restrict__ x, const int* __restrict__ ei, const int* __restrict__ flagp,
    const unsigned short* __restrict__ wt4, const unsigned short* __restrict__ wt1,
    const unsigned short* __restrict__ wt2,
    const float* __restrict__ b4, const float* __restrict__ b1, const float* __restrict__ b2,
    const float* __restrict__ scale, const float* __restrict__ wf,
    unsigned short* __restrict__ Ybuf, float* __restrict__ stats, float* __restrict__ out, int E)
{
  __shared__ __align__(16) char hA[65536];
  __shared__ __align__(16) char bT[32768];
  __shared__ float sS[2560];

  const int t = threadIdx.x;
  const int m0 = blockIdx.x * 128;

  if (KIND != 0) {
    for (int i = t; i < 2560; i += 512) sS[i] = (i < 2304) ? scale[i] : wf[i - 2304];
  }

  int e = m0 + (t & 127); if (e >= E) e = E - 1;
  int sN, dN;
  if (flagp[0]) { sN = ei[2 * e]; dN = ei[2 * (E + e)]; }
  else          { sN = ei[e];     dN = ei[E + e]; }

  dev_stage_gather(hA, x, sN, dN, t);

  f32x4 acc[4][4];
  dev_gemm_hA(acc, hA, bT, wt4, t);                 // Y4 raw
  if (KIND == 0) { dev_epilogue<false, true>(acc, b4, nullptr, stats, m0, E, t); return; }

  dev_act_to_hA<false>(acc, hA, sS, 0, t);          // h = act4(Y4)

  if (KIND == 5) {
    __syncthreads();                                 // h fully written
    const int wv2 = t >> 6, l2 = t & 63;
#pragma unroll
    for (int u = 0; u < 8; ++u) {
      const int row = wv2 * 16 + u * 2 + (l2 >> 5);
      const int colb = (l2 & 31) * 8;
      const unsigned short* ysrc = Ybuf + (size_t)(m0 + row) * 256 + colb;
      uint4 y = *(const uint4*)ysrc;
      char* hp = hA + row * 512;
      const int off = (colb * 2) ^ ((row & 7) << 4);
      short8 h = *(const short8*)(hp + off);
      float dot = 0.f;
      uint4 o;
      o.x = k5pair(y.x, bfs(h[0]), bfs(h[1]), sS, colb + 0, dot);
      o.y = k5pair(y.y, bfs(h[2]), bfs(h[3]), sS, colb + 2, dot);
      o.z = k5pair(y.z, bfs(h[4]), bfs(h[5]), sS, colb + 4, dot);
      o.w = k5pair(y.w, bfs(h[6]), bfs(h[7]), sS, colb + 6, dot);
      *(uint4*)(hp + off) = o;                       // out1 overwrites h (own chunk)
      dot += __shfl_xor(dot, 1); dot += __shfl_xor(dot, 2); dot += __shfl_xor(dot, 4);
      dot += __shfl_xor(dot, 8); dot += __shfl_xor(dot, 16);
      if ((l2 & 31) == 0 && (m0 + row) < E) atomicAdd(&out[m0 + row], dot);
    }
  } else {
    dev_gemm_hA(acc, hA, bT, wt1, t);               // Y1 raw
    if (KIND == 1) { dev_epilogue<true, true>(acc, b1, Ybuf, stats, m0, E, t); return; }
    if (KIND == 2) { dev_epilogue<false, true>(acc, b1, nullptr, stats, m0, E, t); return; }
    dev_act_to_hA<true>(acc, hA, sS, 768, t);       // out1 = act1(Y1) + h
  }

  dev_gemm_hA(acc, hA, bT, wt2, t);                 // Y2 raw
  if (KIND == 3) { dev_epilogue<false, true>(acc, b2, nullptr, stats, m0, E, t); return; }
  if (KIND == 5) { dev_epilogue<true, true>(acc, b2, Ybuf, stats, m0, E, t); return; }
  dev_dot_emit(acc, hA, sS, out, m0, E, t);         // KIND 4
}

// ---------------- Tier A kernels (stored-Y path) ----------------
__device__ __forceinline__ unsigned int act1p(unsigned int y, const float* sS, int k) {
  return packbf(relu_(fmaf(bflo(y), sS[k], sS[256 + k])),
                relu_(fmaf(bfhi(y), sS[k + 1], sS[256 + k + 1])));
}
__device__ __forceinline__ unsigned int act2p(unsigned int y, unsigned int z, const float* sS, int k) {
  float lo = relu_(fmaf(bflo(y), sS[k], sS[256 + k])) +
             relu_(fmaf(bflo(z), sS[512 + k], sS[768 + k]));
  float hi = relu_(fmaf(bfhi(y), sS[k + 1], sS[256 + k + 1])) +
             relu_(fmaf(bfhi(z), sS[512 + k + 1], sS[768 + k + 1]));
  return packbf(lo, hi);
}

template<int MODE>
__global__ __launch_bounds__(512) void k_gemm(
    const void* __restrict__ A0v, const unsigned short* __restrict__ A1,
    const int* __restrict__ ei, const int* __restrict__ flagp,
    const unsigned short* __restrict__ Wt,
    const float* __restrict__ bias, const float* __restrict__ sc0, const float* __restrict__ sc1,
    unsigned short* __restrict__ Yout, unsigned short* __restrict__ Aout,
    float* __restrict__ stats, int E)
{
  __shared__ __align__(16) char aT[16384];
  __shared__ __align__(16) char bT[32768];
  __shared__ float sS[1024];

  const int t = threadIdx.x;
  const int m0 = blockIdx.x * 128;

  if (MODE >= 1 && t < 256) {
    sS[t] = sc0[t];
    sS[256 + t] = sc0[256 + t];
    if (MODE == 2) { sS[512 + t] = sc1[t]; sS[768 + t] = sc1[256 + t]; }
  }

  const int arow = t & 127;
  const int acg = t >> 7;
  const int brow = t & 255;
  const int bh = t >> 8;

  int sN = 0, dN = 0;
  if (MODE == 0) {
    int e = m0 + arow; if (e >= E) e = E - 1;
    if (flagp[0]) { sN = ei[2 * e]; dN = ei[2 * (E + e)]; }
    else          { sN = ei[e];     dN = ei[E + e]; }
  }

  f32x4 acc[4][4];
  f32x4 zz = {0.f, 0.f, 0.f, 0.f};
#pragma unroll
  for (int i = 0; i < 4; ++i)
#pragma unroll
    for (int j = 0; j < 4; ++j) acc[i][j] = zz;

  const int l = t & 63;
  const int wv = t >> 6;
  const int wr = wv >> 2;
  const int wc = wv & 3;
  const int sw = (l & 7) << 4;

  if (MODE >= 1) __syncthreads();

  for (int ks = 0; ks < 4; ++ks) {
    if (ks) __syncthreads();
    {
      const int kc0 = acg * 2;
      char* ap = aT + arow * 128;
      const int swa = (arow & 7) << 4;
      uint4 v0, v1;
      if (MODE == 0) {
        const float* xf = (const float*)A0v;
        const int node = (ks < 2) ? sN : dN;
        const float* src = xf + node * 128 + (ks & 1) * 64 + kc0 * 8;
        float4 f0 = *(const float4*)(src);
        float4 f1 = *(const float4*)(src + 4);
        float4 f2 = *(const float4*)(src + 8);
        float4 f3 = *(const float4*)(src + 12);
        v0.x = packbf(f0.x, f0.y); v0.y = packbf(f0.z, f0.w);
        v0.z = packbf(f1.x, f1.y); v0.w = packbf(f1.z, f1.w);
        v1.x = packbf(f2.x, f2.y); v1.y = packbf(f2.z, f2.w);
        v1.z = packbf(f3.x, f3.y); v1.w = packbf(f3.z, f3.w);
      } else {
        const unsigned short* Ys = (const unsigned short*)A0v;
        const size_t rb = (size_t)(m0 + arow) * 256 + ks * 64 + kc0 * 8;
        uint4 y0 = *(const uint4*)(Ys + rb);
        uint4 y1 = *(const uint4*)(Ys + rb + 8);
        const int k0 = ks * 64 + kc0 * 8;
        if (MODE == 1) {
          v0.x = act1p(y0.x, sS, k0 + 0);  v0.y = act1p(y0.y, sS, k0 + 2);
          v0.z = act1p(y0.z, sS, k0 + 4);  v0.w = act1p(y0.w, sS, k0 + 6);
          v1.x = act1p(y1.x, sS, k0 + 8);  v1.y = act1p(y1.y, sS, k0 + 10);
          v1.z = act1p(y1.z, sS, k0 + 12); v1.w = act1p(y1.w, sS, k0 + 14);
        } else {
          uint4 z0 = *(const uint4*)(A1 + rb);
          uint4 z1 = *(const uint4*)(A1 + rb + 8);
          v0.x = act2p(y0.x, z0.x, sS, k0 + 0);  v0.y = act2p(y0.y, z0.y, sS, k0 + 2);
          v0.z = act2p(y0.z, z0.z, sS, k0 + 4);  v0.w = act2p(y0.w, z0.w, sS, k0 + 6);
          v1.x = act2p(y1.x, z1.x, sS, k0 + 8);  v1.y = act2p(y1.y, z1.y, sS, k0 + 10);
          v1.z = act2p(y1.z, z1.z, sS, k0 + 12); v1.w = act2p(y1.w, z1.w, sS, k0 + 14);
          unsigned short* Ao = Aout + rb;
          *(uint4*)(Ao) = v0;
          *(uint4*)(Ao + 8) = v1;
        }
      }
      *(uint4*)(ap + ((kc0 * 16) ^ swa)) = v0;
      *(uint4*)(ap + (((kc0 + 1) * 16) ^ swa)) = v1;
    }
    {
      const unsigned short* src = Wt + brow * 256 + ks * 64 + bh * 32;
      uint4 b0 = *(const uint4*)(src);
      uint4 b1 = *(const uint4*)(src + 8);
      uint4 b2 = *(const uint4*)(src + 16);
      uint4 b3 = *(const uint4*)(src + 24);
      char* bp = bT + brow * 128;
      const int swb = (brow & 7) << 4;
      const int kcb = bh * 4;
      *(uint4*)(bp + (((kcb + 0) * 16) ^ swb)) = b0;
      *(uint4*)(bp + (((kcb + 1) * 16) ^ swb)) = b1;
      *(uint4*)(bp + (((kcb + 2) * 16) ^ swb)) = b2;
      *(uint4*)(bp + (((kcb + 3) * 16) ^ swb)) = b3;
    }
    __syncthreads();
    {
      const int ar = wr * 64 + (l & 15);
      const int bn = wc * 64 + (l & 15);
#pragma unroll
      for (int kk = 0; kk < 2; ++kk) {
        const int koff = kk * 64 + ((l >> 4) << 4);
        short8 af[4], bfr[4];
#pragma unroll
        for (int i = 0; i < 4; ++i)
          af[i] = *(const short8*)(aT + (ar + i * 16) * 128 + (koff ^ sw));
#pragma unroll
        for (int j = 0; j < 4; ++j)
          bfr[j] = *(const short8*)(bT + (bn + j * 16) * 128 + (koff ^ sw));
#pragma unroll
        for (int i = 0; i < 4; ++i)
#pragma unroll
          for (int j = 0; j < 4; ++j)
            acc[i][j] = __builtin_amdgcn_mfma_f32_16x16x32_bf16(af[i], bfr[j], acc[i][j], 0, 0, 0);
      }
    }
  }
  dev_epilogue<true, true>(acc, bias, Yout, stats, m0, E, t);
}

__device__ __forceinline__ float gp(unsigned int u2, unsigned int o1,
                                    const float* sS, int k, float acc) {
  float lo = relu_(fmaf(bflo(u2), sS[k], sS[256 + k])) + bflo(o1);
  float hi = relu_(fmaf(bfhi(u2), sS[k + 1], sS[256 + k + 1])) + bfhi(o1);
  return fmaf(lo, sS[512 + k], fmaf(hi, sS[512 + k + 1], acc));
}

__global__ __launch_bounds__(256) void k_gemv(
    const unsigned short* __restrict__ Y2, const unsigned short* __restrict__ O1,
    const float* __restrict__ sc2, const float* __restrict__ wf, const float* __restrict__ bfp,
    float* __restrict__ out, int E)
{
  __shared__ float sS[768];
  const int t = threadIdx.x;
  sS[t] = sc2[t]; sS[256 + t] = sc2[256 + t]; sS[512 + t] = wf[t];
  __syncthreads();
  const int e = blockIdx.x * 64 + (t >> 2);
  const int p = t & 3;
  const size_t rb = (size_t)e * 256 + p * 64;
  const unsigned short* r2 = Y2 + rb;
  const unsigned short* r1 = O1 + rb;
  float acc = 0.f;
#pragma unroll
  for (int m = 0; m < 8; ++m) {
    uint4 a = *(const uint4*)(r2 + m * 8);
    uint4 b = *(const uint4*)(r1 + m * 8);
    const int k0 = p * 64 + m * 8;
    acc = gp(a.x, b.x, sS, k0 + 0, acc);
    acc = gp(a.y, b.y, sS, k0 + 2, acc);
    acc = gp(a.z, b.z, sS, k0 + 4, acc);
    acc = gp(a.w, b.w, sS, k0 + 6, acc);
  }
  acc += __shfl_xor(acc, 1);
  acc += __shfl_xor(acc, 2);
  if (p == 0 && e < E) out[e] = acc + bfp[0];
}

// Tier B final scan: out[e] += relu(bn2(Y2[e,:])) . wf
__global__ __launch_bounds__(256) void k_scan2(
    const unsigned short* __restrict__ Y2, const float* __restrict__ sc2,
    const float* __restrict__ wf, float* __restrict__ out, int E)
{
  __shared__ float sS[768];
  const int t = threadIdx.x;
  sS[t] = sc2[t]; sS[256 + t] = sc2[256 + t]; sS[512 + t] = wf[t];
  __syncthreads();
  const int e = blockIdx.x * 64 + (t >> 2);
  const int p = t & 3;
  const size_t rb = (size_t)e * 256 + p * 64;
  const unsigned short* r2 = Y2 + rb;
  float acc = 0.f;
#pragma unroll
  for (int m = 0; m < 8; ++m) {
    uint4 a = *(const uint4*)(r2 + m * 8);
    const int k0 = p * 64 + m * 8;
    float lo, hi;
    lo = relu_(fmaf(bflo(a.x), sS[k0 + 0], sS[256 + k0 + 0]));
    hi = relu_(fmaf(bfhi(a.x), sS[k0 + 1], sS[256 + k0 + 1]));
    acc = fmaf(lo, sS[512 + k0 + 0], fmaf(hi, sS[512 + k0 + 1], acc));
    lo = relu_(fmaf(bflo(a.y), sS[k0 + 2], sS[256 + k0 + 2]));
    hi = relu_(fmaf(bfhi(a.y), sS[k0 + 3], sS[256 + k0 + 3]));
    acc = fmaf(lo, sS[512 + k0 + 2], fmaf(hi, sS[512 + k0 + 3], acc));
    lo = relu_(fmaf(bflo(a.z), sS[k0 + 4], sS[256 + k0 + 4]));
    hi = relu_(fmaf(bfhi(a.z), sS[k0 + 5], sS[256 + k0 + 5]));
    acc = fmaf(lo, sS[512 + k0 + 4], fmaf(hi, sS[512 + k0 + 5], acc));
    lo = relu_(fmaf(bflo(a.w), sS[k0 + 6], sS[256 + k0 + 6]));
    hi = relu_(fmaf(bfhi(a.w), sS[k0 + 7], sS[256 + k0 + 7]));
    acc = fmaf(lo, sS[512 + k0 + 6], fmaf(hi, sS[512 + k0 + 7], acc));
  }
  acc += __shfl_xor(acc, 1);
  acc += __shfl_xor(acc, 2);
  if (p == 0 && e < E) out[e] = out[e] + acc;   // single writer per e
}

extern "C" void kernel_launch(void* const* d_in, const int* in_sizes, int n_in,
                              void* d_out, int out_size, void* d_ws, size_t ws_size,
                              hipStream_t stream) {
  const float* x   = (const float*)d_in[0];
  const int*   ei  = (const int*)d_in[1];
  const float* W4  = (const float*)d_in[2];
  const float* b4  = (const float*)d_in[3];
  const float* g4  = (const float*)d_in[4];
  const float* be4 = (const float*)d_in[5];
  const float* W1  = (const float*)d_in[6];
  const float* b1  = (const float*)d_in[7];
  const float* g1  = (const float*)d_in[8];
  const float* be1 = (const float*)d_in[9];
  const float* W2  = (const float*)d_in[10];
  const float* b2  = (const float*)d_in[11];
  const float* g2  = (const float*)d_in[12];
  const float* be2 = (const float*)d_in[13];
  const float* Wf  = (const float*)d_in[14];
  const float* bfp = (const float*)d_in[15];
  float* out = (float*)d_out;

  const int E = out_size;                 // output length IS the edge count
  const int MTg = (E + 127) / 128;
  const float invE = 1.0f / (float)E;

  char* ws = (char*)d_ws;
  unsigned short* wt4 = (unsigned short*)(ws);
  unsigned short* wt1 = (unsigned short*)(ws + 131072);
  unsigned short* wt2 = (unsigned short*)(ws + 262144);
  float* stats = (float*)(ws + 393216);   // 3 x (sum[256], sumsq[256])
  float* scale = (float*)(ws + 399360);   // 3 x (a[256], c_std[256], c_b[256])
  int*   flag  = (int*)(ws + 408576);
  const size_t fixed = 409600;
  const size_t ypad = (size_t)MTg * 65536;
  unsigned short* bufA = (unsigned short*)(ws + fixed);
  unsigned short* bufB = (unsigned short*)(ws + fixed + ypad);

  if (ws_size < fixed) {                  // hostile ws: produce finite output, no crash
    k_zero<<<(E + 255) / 256, 256, 0, stream>>>(out, bfp, E);
    return;
  }

  const bool tierA = ws_size >= fixed + 2 * ypad;
  const bool tierB = !tierA && ws_size >= fixed + ypad;

  k_init<<<1, 256, 0, stream>>>(ei, stats, flag);
  k_prep<<<192, 256, 0, stream>>>(W4, W1, W2, wt4, wt1, wt2);

  if (tierA) {
    k_gemm<0><<<MTg, 512, 0, stream>>>((const void*)x, nullptr, ei, flag, wt4, b4,
                                       nullptr, nullptr, bufA, nullptr, stats, E);
    k_stats<<<1, 256, 0, stream>>>(stats, g4, be4, b4, scale, invE);
    k_gemm<1><<<MTg, 512, 0, stream>>>((const void*)bufA, nullptr, nullptr, flag, wt1, b1,
                                       scale, nullptr, bufB, nullptr, stats + 512, E);
    k_stats<<<1, 256, 0, stream>>>(stats + 512, g1, be1, b1, scale + 768, invE);
    k_gemm<2><<<MTg, 512, 0, stream>>>((const void*)bufB, bufA, nullptr, flag, wt2, b2,
                                       scale + 768, scale, bufB, bufA, stats + 1024, E);
    k_stats<<<1, 256, 0, stream>>>(stats + 1024, g2, be2, b2, scale + 1536, invE);
    k_gemv<<<(E + 63) / 64, 256, 0, stream>>>(bufB, bufA, scale + 1536, Wf, bfp, out, E);
  } else if (tierB) {
    k_zero<<<(E + 255) / 256, 256, 0, stream>>>(out, bfp, E);
    k_chain<0><<<MTg, 512, 0, stream>>>(x, ei, flag, wt4, wt1, wt2, b4, b1, b2,
                                        scale, Wf, nullptr, stats, out, E);
    k_stats<<<1, 256, 0, stream>>>(stats, g4, be4, b4, scale, invE);
    k_chain<1><<<MTg, 512, 0, stream>>>(x, ei, flag, wt4, wt1, wt2, b4, b1, b2,
                                        scale, Wf, bufA, stats + 512, out, E);
    k_stats<<<1, 256, 0, stream>>>(stats + 512, g1, be1, b1, scale + 768, invE);
    k_chain<5><<<MTg, 512, 0, stream>>>(x, ei, flag, wt4, wt1, wt2, b4, b1, b2,
                                        scale, Wf, bufA, stats + 1024, out, E);
    k_stats<<<1, 256, 0, stream>>>(stats + 1024, g2, be2, b2, scale + 1536, invE);
    k_scan2<<<(E + 63) / 64, 256, 0, stream>>>(bufA, scale + 1536, Wf, out, E);
  } else {
    k_zero<<<(E + 255) / 256, 256, 0, stream>>>(out, bfp, E);
    k_chain<0><<<MTg, 512, 0, stream>>>(x, ei, flag, wt4, wt1, wt2, b4, b1, b2,
                                        scale, Wf, nullptr, stats, out, E);
    k_stats<<<1, 256, 0, stream>>>(stats, g4, be4, b4, scale, invE);
    k_chain<2><<<MTg, 512, 0, stream>>>(x, ei, flag, wt4, wt1, wt2, b4, b1, b2,
                                        scale, Wf, nullptr, stats + 512, out, E);
    k_stats<<<1, 256, 0, stream>>>(stats + 512, g1, be1, b1, scale + 768, invE);
    k_chain<3><<<MTg, 512, 0, stream>>>(x, ei, flag, wt4, wt1, wt2, b4, b1, b2,
                                        scale, Wf, nullptr, stats + 1024, out, E);
    k_stats<<<1, 256, 0, stream>>>(stats + 1024, g2, be2, b2, scale + 1536, invE);
    k_chain<4><<<MTg, 512, 0, stream>>>(x, ei, flag, wt4, wt1, wt2, b4, b1, b2,
                                        scale, Wf, nullptr, nullptr, out, E);
  }
}